// Round 3
// baseline (1693.424 us; speedup 1.0000x reference)
//
#include <hip/hip_runtime.h>
#include <math.h>

#define HW 65536
#define NS 5
#define DFEAT 128
#define CMID 64
#define TEMPER 0.1f
#define BNEPS 1e-5f

typedef __attribute__((ext_vector_type(8))) short bf16x8;
typedef __attribute__((ext_vector_type(4))) float f32x4;

__device__ inline short f2bf(float f) {
  union { float f; unsigned u; } v; v.f = f;
  unsigned r = v.u + 0x7fffu + ((v.u >> 16) & 1u);
  return (short)(r >> 16);
}
__device__ inline float bf2f(unsigned short h) {
  union { unsigned u; float f; } v; v.u = ((unsigned)h) << 16;
  return v.f;
}
__device__ inline unsigned pack2bf(float f0, float f1) {
  return ((unsigned)(unsigned short)f2bf(f0)) | (((unsigned)(unsigned short)f2bf(f1)) << 16);
}

union U16B { int4 v; unsigned short s[8]; };

// ---------------------------------------------------------------- zero
__global__ void zero_kernel(float* __restrict__ p, int n) {
  int i = blockIdx.x * blockDim.x + threadIdx.x;
  if (i < n) p[i] = 0.f;
}

// ---------------------------------------------------------------- weight prep (all 3 granularities, one launch)
// w1p[g]: [9][KS][2 hl][64 n][32 k] at W1OFF[g]; w2p[g]: [2 ks][2 hl][128 n][32 k] at W2OFF[g]
__global__ void wprep_all_kernel(const float* __restrict__ w1_0, const float* __restrict__ w1_1,
                                 const float* __restrict__ w1_2, const float* __restrict__ w2_0,
                                 const float* __restrict__ w2_1, const float* __restrict__ w2_2,
                                 unsigned short* __restrict__ wp) {
  int idx = blockIdx.x * 256 + threadIdx.x;
  if (idx < 147456) {
    int g, local, KS, C;
    const float* w1;
    if (idx < 73728)       { g = 0; local = idx;          KS = 2; C = 64; w1 = w1_0; }
    else if (idx < 110592) { g = 1; local = idx - 73728;  KS = 1; C = 32; w1 = w1_1; }
    else                   { g = 2; local = idx - 110592; KS = 1; C = 16; w1 = w1_2; }
    int kl = local & 31; int t = local >> 5;
    int nn = t & 63; t >>= 6;
    int hl = t & 1;  t >>= 1;
    int ks = t % KS; int s = t / KS;
    int ic = ks * 32 + kl;
    float v = (ic < C) ? w1[((size_t)nn * C + ic) * 9 + s] : 0.f;
    short hi = f2bf(v);
    short r = (hl == 0) ? hi : f2bf(v - bf2f((unsigned short)hi));
    wp[idx] = (unsigned short)r;
  } else if (idx < 196608) {
    int i2 = idx - 147456;
    int g = i2 >> 14, j = i2 & 16383;
    const float* w2 = (g == 0) ? w2_0 : (g == 1) ? w2_1 : w2_2;
    int kl = j & 31;
    int nn = (j >> 5) & 127;
    int hl = (j >> 12) & 1;
    int ks = j >> 13;
    float v = w2[nn * 64 + ks * 32 + kl];
    short hi = f2bf(v);
    short r = (hl == 0) ? hi : f2bf(v - bf2f((unsigned short)hi));
    wp[idx] = (unsigned short)r;
  }
}

// ---------------------------------------------------------------- conv3x3 via MFMA, fused NCHW->bf16 transpose
// grid (8,32,5), block 256. Tile 32x8 px x 64 oc. Swizzled LDS; BN1 stats fused; h1 NHWC bf16.
template<int C, int CP>
__global__ __launch_bounds__(256, 3) void conv_mfma_kernel(
    const float* __restrict__ x,             // [5][C][256][256] fp32
    const unsigned short* __restrict__ w1p,  // [9][KS][2][64][32] bf16
    unsigned short* __restrict__ h1,         // [5][HW][64] bf16
    float* __restrict__ st)                  // [5][64][2]
{
  constexpr int KS = CP / 32;
  constexpr int XS = 10 * 34 * CP;
  constexpr int HS = 256 * 72;
  constexpr int UNI = (XS > HS) ? XS : HS;
  __shared__ __align__(16) unsigned short smem[UNI];
  __shared__ float reds[4][64], redq[4][64];

  const int tid = threadIdx.x;
  const int lane = tid & 63, wave = tid >> 6;
  const int lanen = lane & 15, quad = lane >> 4;
  const int tx = blockIdx.x, ty = blockIdx.y, n = blockIdx.z;
  const int x0 = tx * 32, y0 = ty * 8;

  // ---- fused-transpose staging: task = (row 0..9) x (channel pair)
  {
    constexpr int HALF = CP / 2;
    for (int idx = tid; idx < 10 * HALF; idx += 256) {
      const int cp  = idx % HALF;
      const int row = idx / HALF;
      const int c0  = cp * 2;
      const int gy  = y0 - 1 + row;
      const int grp = c0 >> 3;
      const int sub = c0 & 7;
      const bool rowok = ((unsigned)gy < 256u);
      const bool k0 = rowok && (c0 < C);
      const bool k1 = rowok && (c0 + 1 < C);
      const float* g0 = x + (size_t)(n * C + c0) * HW + gy * 256 + x0;
      const float* g1 = g0 + HW;
      unsigned short* base = smem + (row * 34) * CP;
      const int rp = (CP == 32) ? ((row & 1) << 1) : 0;
      {  // col 0 (gx = x0-1)
        float v0 = (k0 && tx > 0) ? g0[-1] : 0.f;
        float v1 = (k1 && tx > 0) ? g1[-1] : 0.f;
        int ph = (CP == 64) ? grp : ((grp ^ rp) & 3);
        *(unsigned*)(base + ph * 8 + sub) = pack2bf(v0, v1);
      }
      {  // col 33 (gx = x0+32)
        float v0 = (k0 && tx < 7) ? g0[32] : 0.f;
        float v1 = (k1 && tx < 7) ? g1[32] : 0.f;
        int ph = (CP == 64) ? (grp ^ 1) : ((grp ^ 1 ^ rp) & 3);
        *(unsigned*)(base + 33 * CP + ph * 8 + sub) = pack2bf(v0, v1);
      }
#pragma unroll
      for (int v4 = 0; v4 < 8; ++v4) {  // cols 1..32
        float4 f0 = k0 ? ((const float4*)g0)[v4] : make_float4(0.f, 0.f, 0.f, 0.f);
        float4 f1 = k1 ? ((const float4*)g1)[v4] : make_float4(0.f, 0.f, 0.f, 0.f);
        const float* a0 = (const float*)&f0;
        const float* a1 = (const float*)&f1;
#pragma unroll
        for (int k = 0; k < 4; ++k) {
          int col = 1 + v4 * 4 + k;
          int ph = (CP == 64) ? (grp ^ (col & 7)) : ((grp ^ (col & 3) ^ rp) & 3);
          *(unsigned*)(base + col * CP + ph * 8 + sub) = pack2bf(a0[k], a1[k]);
        }
      }
    }
  }
  __syncthreads();

  // ---- MFMA main loop
  f32x4 acc[4][4];
#pragma unroll
  for (int t = 0; t < 4; ++t)
#pragma unroll
    for (int nt = 0; nt < 4; ++nt)
      acc[t][nt] = (f32x4){0.f, 0.f, 0.f, 0.f};

#pragma unroll
  for (int s = 0; s < 9; ++s) {
    const int dy = s / 3, dx = s % 3;
#pragma unroll
    for (int ks = 0; ks < KS; ++ks) {
      bf16x8 af[4];
#pragma unroll
      for (int t = 0; t < 4; ++t) {
        const int row = wave * 2 + (t >> 1) + dy;
        const int col = (t & 1) * 16 + lanen + dx;
        int ph;
        if (CP == 64) ph = (ks * 4 + quad) ^ (col & 7);
        else          ph = (quad ^ (col & 3) ^ ((row & 1) << 1)) & 3;
        af[t] = *(const bf16x8*)(smem + (row * 34 + col) * CP + ph * 8);
      }
#pragma unroll
      for (int hl = 0; hl < 2; ++hl) {
        const unsigned short* wb = w1p + ((((s * KS + ks) * 2 + hl) * 64) + lanen) * 32 + quad * 8;
#pragma unroll
        for (int nt = 0; nt < 4; ++nt) {
          bf16x8 bf = *(const bf16x8*)(wb + nt * 16 * 32);
#pragma unroll
          for (int t = 0; t < 4; ++t)
            acc[t][nt] = __builtin_amdgcn_mfma_f32_16x16x32_bf16(af[t], bf, acc[t][nt], 0, 0, 0);
        }
      }
    }
  }

  // ---- BN1 stats
#pragma unroll
  for (int nt = 0; nt < 4; ++nt) {
    float s = 0.f, q = 0.f;
#pragma unroll
    for (int t = 0; t < 4; ++t)
#pragma unroll
      for (int r = 0; r < 4; ++r) {
        float v = acc[t][nt][r];
        s += v; q += v * v;
      }
    s += __shfl_xor(s, 16); s += __shfl_xor(s, 32);
    q += __shfl_xor(q, 16); q += __shfl_xor(q, 32);
    if (lane < 16) { reds[wave][nt * 16 + lanen] = s; redq[wave][nt * 16 + lanen] = q; }
  }
  __syncthreads();
  if (tid < 64) {
    float s = reds[0][tid] + reds[1][tid] + reds[2][tid] + reds[3][tid];
    float q = redq[0][tid] + redq[1][tid] + redq[2][tid] + redq[3][tid];
    atomicAdd(&st[(n * 64 + tid) * 2 + 0], s);
    atomicAdd(&st[(n * 64 + tid) * 2 + 1], q);
  }

  // ---- h1 store via LDS transpose (smem reused; all waves past barrier above)
#pragma unroll
  for (int t = 0; t < 4; ++t)
#pragma unroll
    for (int nt = 0; nt < 4; ++nt)
#pragma unroll
      for (int r = 0; r < 4; ++r) {
        int pix = wave * 64 + t * 16 + quad * 4 + r;
        smem[pix * 72 + nt * 16 + lanen] = (unsigned short)f2bf(acc[t][nt][r]);
      }
  __syncthreads();
#pragma unroll
  for (int it = 0; it < 8; ++it) {
    int idx = it * 256 + tid;
    int ocg = idx & 7, pix = idx >> 3;
    int py = pix >> 5, px = pix & 31;
    int4 v = *(const int4*)(smem + pix * 72 + ocg * 8);
    *(int4*)(h1 + ((size_t)n * HW + (y0 + py) * 256 + x0 + px) * 64 + ocg * 8) = v;
  }
}

// ---------------------------------------------------------------- stage 2 GEMM via MFMA, BN params in-kernel
// grid (512, 5), block 256. Tile 128 px x 128 oc; wave = 64px x 64oc.
template<bool GAP>
__global__ __launch_bounds__(256, 3) void stage2_mfma_kernel(
    const unsigned short* __restrict__ h1,   // [5][HW][64] bf16
    const unsigned short* __restrict__ w2p,  // [2][2][128][32] bf16
    const float* __restrict__ st1,           // [5][64][2]
    const float* __restrict__ st2,           // [5][128][2] (GAP only)
    const float* __restrict__ gm1, const float* __restrict__ bt1,
    const float* __restrict__ gm2, const float* __restrict__ bt2,
    float* __restrict__ outp,                // st2 or gap
    int batchmode)
{
  __shared__ __align__(16) unsigned short acts[128 * 64];
  __shared__ float red[4][64], redq[4][64];
  const int tid = threadIdx.x;
  const int lane = tid & 63, wave = tid >> 6;
  const int lanen = lane & 15, quad = lane >> 4;
  const int n = blockIdx.y;
  const int pix0 = blockIdx.x * 128;

  // ---- BN1 params for this thread's channel group, from raw stats
  const int cg = tid & 7;
  float a1c[8], b1c[8];
#pragma unroll
  for (int j = 0; j < 8; ++j) {
    int ch = cg * 8 + j;
    float s, q, cnt;
    if (batchmode) {
      s = 0.f; q = 0.f;
      for (int m = 0; m < NS; ++m) { s += st1[(m * 64 + ch) * 2]; q += st1[(m * 64 + ch) * 2 + 1]; }
      cnt = (float)NS * (float)HW;
    } else {
      s = st1[(n * 64 + ch) * 2]; q = st1[(n * 64 + ch) * 2 + 1];
      cnt = (float)HW;
    }
    float mean = s / cnt;
    float var = q / cnt - mean * mean;
    float iv = rsqrtf(var + BNEPS);
    a1c[j] = gm1[ch] * iv;
    b1c[j] = bt1[ch] - mean * a1c[j];
  }

  // ---- stage h1 tile with BN1+ReLU, swizzled
  const unsigned short* hb = h1 + ((size_t)n * HW + pix0) * 64;
#pragma unroll
  for (int it = 0; it < 4; ++it) {
    int idx = it * 256 + tid;
    int pix = idx >> 3;              // idx&7 == cg
    U16B in, o;
    in.v = *(const int4*)(hb + pix * 64 + cg * 8);
#pragma unroll
    for (int j = 0; j < 8; ++j) {
      float f = bf2f(in.s[j]);
      o.s[j] = (unsigned short)f2bf(fmaxf(a1c[j] * f + b1c[j], 0.f));
    }
    int ph = cg ^ (pix & 7);
    *(int4*)(acts + pix * 64 + ph * 8) = o.v;
  }
  __syncthreads();

  // ---- MFMA: wave covers px half (wave&1), oc half (wave>>1)
  const int pb = (wave & 1) * 64;
  const int ob = (wave >> 1) * 64;
  f32x4 acc[4][4];
#pragma unroll
  for (int mt = 0; mt < 4; ++mt)
#pragma unroll
    for (int nt = 0; nt < 4; ++nt)
      acc[mt][nt] = (f32x4){0.f, 0.f, 0.f, 0.f};

#pragma unroll
  for (int ks = 0; ks < 2; ++ks) {
    bf16x8 af[4];
#pragma unroll
    for (int mt = 0; mt < 4; ++mt) {
      int pix = pb + mt * 16 + lanen;
      int ph = (ks * 4 + quad) ^ (pix & 7);
      af[mt] = *(const bf16x8*)(acts + pix * 64 + ph * 8);
    }
#pragma unroll
    for (int hl = 0; hl < 2; ++hl) {
      const unsigned short* wb = w2p + (((ks * 2 + hl) * 128) + ob + lanen) * 32 + quad * 8;
#pragma unroll
      for (int nt = 0; nt < 4; ++nt) {
        bf16x8 bf = *(const bf16x8*)(wb + nt * 16 * 32);
#pragma unroll
        for (int mt = 0; mt < 4; ++mt)
          acc[mt][nt] = __builtin_amdgcn_mfma_f32_16x16x32_bf16(af[mt], bf, acc[mt][nt], 0, 0, 0);
      }
    }
  }

  if constexpr (GAP) {
#pragma unroll
    for (int nt = 0; nt < 4; ++nt) {
      const int o = ob + nt * 16 + lanen;
      float s2, q2, cnt2;
      if (batchmode) {
        s2 = 0.f; q2 = 0.f;
        for (int m = 0; m < NS; ++m) { s2 += st2[(m * 128 + o) * 2]; q2 += st2[(m * 128 + o) * 2 + 1]; }
        cnt2 = (float)NS * (float)HW;
      } else {
        s2 = st2[(n * 128 + o) * 2]; q2 = st2[(n * 128 + o) * 2 + 1];
        cnt2 = (float)HW;
      }
      float mean = s2 / cnt2;
      float var = q2 / cnt2 - mean * mean;
      float iv = rsqrtf(var + BNEPS);
      float a2 = gm2[o] * iv;
      float b2 = bt2[o] - mean * a2;
      float s = 0.f;
#pragma unroll
      for (int mt = 0; mt < 4; ++mt)
#pragma unroll
        for (int r = 0; r < 4; ++r)
          s += fmaxf(a2 * acc[mt][nt][r] + b2, 0.f);
      s += __shfl_xor(s, 16); s += __shfl_xor(s, 32);
      if (lane < 16) red[wave][nt * 16 + lanen] = s;
    }
    __syncthreads();
    if (tid < 128) {
      int oh = tid >> 6, ol = tid & 63;
      atomicAdd(&outp[n * DFEAT + tid], red[oh * 2][ol] + red[oh * 2 + 1][ol]);
    }
  } else {
#pragma unroll
    for (int nt = 0; nt < 4; ++nt) {
      float s = 0.f, q = 0.f;
#pragma unroll
      for (int mt = 0; mt < 4; ++mt)
#pragma unroll
        for (int r = 0; r < 4; ++r) {
          float v = acc[mt][nt][r];
          s += v; q += v * v;
        }
      s += __shfl_xor(s, 16); s += __shfl_xor(s, 32);
      q += __shfl_xor(q, 16); q += __shfl_xor(q, 32);
      if (lane < 16) { red[wave][nt * 16 + lanen] = s; redq[wave][nt * 16 + lanen] = q; }
    }
    __syncthreads();
    if (tid < 128) {
      int oh = tid >> 6, ol = tid & 63;
      atomicAdd(&outp[(n * DFEAT + tid) * 2 + 0], red[oh * 2][ol] + red[oh * 2 + 1][ol]);
      atomicAdd(&outp[(n * DFEAT + tid) * 2 + 1], redq[oh * 2][ol] + redq[oh * 2 + 1][ol]);
    }
  }
}

// ---------------------------------------------------------------- final loss (feat-normalize folded in)
__global__ __launch_bounds__(256) void loss_kernel(const float* __restrict__ gap,
                                                   const int* __restrict__ dm,
                                                   float* __restrict__ out)
{
  __shared__ float F[3840];   // [e=g*2+br][n][128]
  __shared__ float S[75], X[45], cnt[15], ltab[15], inv[30];
  const int tid = threadIdx.x;
  for (int i = tid; i < 3840; i += 256) F[i] = gap[i] * (1.0f / (float)HW);
  if (tid < 15) cnt[tid] = 0.f;
  __syncthreads();
  if (tid < 30) {
    float q = 0.f;
    for (int d = 0; d < 128; ++d) { float v = F[tid * 128 + d]; q += v * v; }
    inv[tid] = 1.0f / fmaxf(sqrtf(q), 1e-12f);
  }
  __syncthreads();
  for (int i = tid; i < 3840; i += 256) F[i] *= inv[i >> 7];
  __syncthreads();
  if (tid < 75) {
    int g = tid / 25, i = (tid / 5) % 5, j = tid % 5;
    const float* q = &F[(2 * g) * 640 + i * 128];
    const float* k = &F[(2 * g + 1) * 640 + j * 128];
    float s = 0.f;
    for (int d = 0; d < 128; ++d) s += q[d] * k[d];
    S[tid] = s;
  } else if (tid < 120) {
    int u = tid - 75;
    int g = u / 15, i = (u % 15) / 3, h = u % 3;
    const float* q = &F[(2 * g) * 640 + i * 128];
    const float* k = &F[(2 * h + 1) * 640 + i * 128];
    float s = 0.f;
    for (int d = 0; d < 128; ++d) s += q[d] * k[d];
    X[u] = s;
  }
  {
    int a = tid >> 6, l = tid & 63;
    int c0 = 0, c1 = 0, c2 = 0;
    const int* base = dm + a * 16384;
    for (int k = 0; k < 256; ++k) {
      int v = base[k * 64 + l];
      c0 += (v == 1); c1 += (v == 2); c2 += (v == 3);
    }
    atomicAdd(&cnt[0 * 5 + a + 1], (float)c0);
    atomicAdd(&cnt[1 * 5 + a + 1], (float)c1);
    atomicAdd(&cnt[2 * 5 + a + 1], (float)c2);
  }
  __syncthreads();
  if (tid < 15) {
    int g = tid / 5, i = tid % 5;
    const float inv_t = 1.0f / TEMPER;
    float lg[9];
    lg[0] = S[g * 25 + i * 5 + i] * inv_t;
    for (int j = 0; j < 5; ++j) lg[1 + j] = (j == i) ? (-1e9f * inv_t) : S[g * 25 + i * 5 + j] * inv_t;
    for (int h = 0; h < 3; ++h) lg[6 + h] = (h == g) ? (-1e9f * inv_t) : X[g * 15 + i * 3 + h] * inv_t;
    float m = lg[0];
    for (int k = 1; k < 9; ++k) m = fmaxf(m, lg[k]);
    float se = 0.f;
    for (int k = 0; k < 9; ++k) se += expf(lg[k] - m);
    ltab[tid] = -lg[0] + m + logf(se);
  }
  __syncthreads();
  if (tid == 0) {
    float tot = 0.f, acc = 0.f;
    for (int k = 0; k < 15; ++k) { tot += cnt[k]; acc += cnt[k] * ltab[k]; }
    out[0] = (tot > 0.f) ? acc / fmaxf(tot, 1.f) : 0.f;
  }
}

// ---------------------------------------------------------------- host orchestration
extern "C" void kernel_launch(void* const* d_in, const int* in_sizes, int n_in,
                              void* d_out, int out_size, void* d_ws, size_t ws_size,
                              hipStream_t stream) {
  (void)in_sizes; (void)n_in; (void)out_size; (void)ws_size;

  const float* sp[3]  = {(const float*)d_in[0],  (const float*)d_in[8],  (const float*)d_in[16]};
  const float* dn[3]  = {(const float*)d_in[1],  (const float*)d_in[9],  (const float*)d_in[17]};
  const float* w1[3]  = {(const float*)d_in[2],  (const float*)d_in[10], (const float*)d_in[18]};
  const float* gm1[3] = {(const float*)d_in[3],  (const float*)d_in[11], (const float*)d_in[19]};
  const float* bt1[3] = {(const float*)d_in[4],  (const float*)d_in[12], (const float*)d_in[20]};
  const float* w2[3]  = {(const float*)d_in[5],  (const float*)d_in[13], (const float*)d_in[21]};
  const float* gm2[3] = {(const float*)d_in[6],  (const float*)d_in[14], (const float*)d_in[22]};
  const float* bt2[3] = {(const float*)d_in[7],  (const float*)d_in[15], (const float*)d_in[23]};
  const int*   dm     = (const int*)d_in[24];

  float* ws_f = (float*)d_ws;
  unsigned short* h1u = (unsigned short*)ws_f;                 // 20,971,520 shorts
  unsigned short* wp  = (unsigned short*)(ws_f + 10485760);    // 196,608 shorts
  float* st1_all = ws_f + 10485760 + 98304;                    // [6][5][64][2]  = 3840
  float* st2_all = st1_all + 3840;                             // [6][5][128][2] = 7680
  float* gap     = st2_all + 7680;                             // [6][5][128]    = 3840
  const int W1OFF[3] = {0, 73728, 110592};
  const int W2OFF[3] = {147456, 163840, 180224};

  zero_kernel<<<60, 256, 0, stream>>>(st1_all, 15360);
  wprep_all_kernel<<<768, 256, 0, stream>>>(w1[0], w1[1], w1[2], w2[0], w2[1], w2[2], wp);

  for (int g = 0; g < 3; ++g) {
    for (int br = 0; br < 2; ++br) {
      const int e = g * 2 + br;
      const float* x = br ? dn[g] : sp[g];
      float* st1 = st1_all + e * 640;
      float* st2 = st2_all + e * 1280;

      dim3 cg(8, 32, 5);
      if (g == 0)      conv_mfma_kernel<64, 64><<<cg, 256, 0, stream>>>(x, wp + W1OFF[g], h1u, st1);
      else if (g == 1) conv_mfma_kernel<32, 32><<<cg, 256, 0, stream>>>(x, wp + W1OFF[g], h1u, st1);
      else             conv_mfma_kernel<16, 32><<<cg, 256, 0, stream>>>(x, wp + W1OFF[g], h1u, st1);

      dim3 sg(512, 5);
      stage2_mfma_kernel<false><<<sg, 256, 0, stream>>>(h1u, wp + W2OFF[g], st1, nullptr,
                                                        gm1[g], bt1[g], gm2[g], bt2[g], st2, br);
      stage2_mfma_kernel<true><<<sg, 256, 0, stream>>>(h1u, wp + W2OFF[g], st1, st2,
                                                       gm1[g], bt1[g], gm2[g], bt2[g], gap + e * 640, br);
    }
  }

  loss_kernel<<<1, 256, 0, stream>>>(gap, dm, (float*)d_out);
}